// Round 16
// baseline (144.352 us; speedup 1.0000x reference)
//
#include <hip/hip_runtime.h>
#include <hip/hip_bf16.h>

// InfoNCE loss, N=4096, D=1024, TEMP=0.07.
// loss = mean_i( -pos_i + lse_i ), lse over sim rows with diagonal masked.
// Fixed-max LSE (rows unit-norm -> sim <= 1/T): partials are order-independent.
// Symmetry via 128x128 tiles, upper triangle (J >= I).
//
// R16: R13 skeleton (128x128 tile, 4 waves 2x2, ring-2 dbuf 32 KiB,
// vmcnt(4) counted gate, 4 blocks/CU, zero-conflict XOR swizzle, plane-store
// epilogue, Ji-bounded reduce) with the inner math moved to
// mfma_f32_32x32x16_bf16: 8 MFMA/step (64.6 issue-cyc) instead of 16
// (77.6), same LDS traffic, higher ceiling. Wave-tile 64x64 = 2x2 frags of
// 32x32; acc = 2x2 f32x16 = 64 AGPR (unchanged). A/B frag: row=lane&31,
// k=(lane>>5)*8+j (verified pattern, R6). C/D: col=lane&31,
// row=(reg&3)+8*(reg>>2)+4*(lane>>5) (verified, R6/m74/m101).

typedef __attribute__((ext_vector_type(8))) short bf16x8;
typedef __attribute__((ext_vector_type(16))) float f32x16;

#define NN 4096
#define TWO_N 8192
#define DIM 1024
#define TEMP_INV 14.285714285714286f
#define EXP_SCALE 20.609929155566303f /* log2(e)/0.07 */
#define NT 64     /* tiles of 128 per dim */
#define NBLK 2080 /* 64*65/2 upper-tri tiles; 2080 % 8 == 0 -> bijective */
#define SLOT 8192 /* shorts per slot: A[128][32] + B[128][32] = 16 KB */

#define GLD16(g, l)                                                          \
  __builtin_amdgcn_global_load_lds(                                          \
      (const __attribute__((address_space(1))) void*)(g),                    \
      (__attribute__((address_space(3))) void*)(l), 16, 0, 0)

__device__ __forceinline__ unsigned short f2bf(float f) {
  unsigned int u = __float_as_uint(f);
  u += 0x7fffu + ((u >> 16) & 1u);  // RNE
  return (unsigned short)(u >> 16);
}

// Fused: fp32->bf16 cast of z=[z1;z2] AND pos[row]=dot(z1,z2)/T (one 32MB read).
__global__ __launch_bounds__(256) void prep_kernel(
    const float* __restrict__ z1, const float* __restrict__ z2,
    unsigned short* __restrict__ zb, float* __restrict__ pos) {
  const int row = blockIdx.x, t = threadIdx.x;
  float4 a = ((const float4*)(z1 + (size_t)row * DIM))[t];
  float4 b = ((const float4*)(z2 + (size_t)row * DIM))[t];
  ushort4 ua = {f2bf(a.x), f2bf(a.y), f2bf(a.z), f2bf(a.w)};
  ushort4 ub = {f2bf(b.x), f2bf(b.y), f2bf(b.z), f2bf(b.w)};
  ((ushort4*)(zb + (size_t)row * DIM))[t] = ua;
  ((ushort4*)(zb + (size_t)(NN + row) * DIM))[t] = ub;
  float s = a.x * b.x + a.y * b.y + a.z * b.z + a.w * b.w;
#pragma unroll
  for (int off = 1; off < 64; off <<= 1) s += __shfl_xor(s, off);
  __shared__ float tmp[4];
  if ((t & 63) == 0) tmp[t >> 6] = s;
  __syncthreads();
  if (t == 0) pos[row] = (tmp[0] + tmp[1] + tmp[2] + tmp[3]) * TEMP_INV;
}

__global__ __launch_bounds__(256, 4) void lse_kernel(
    const unsigned short* __restrict__ zb, float* __restrict__ part) {
  __shared__ unsigned short lds[2 * SLOT];  // 32 KiB; 4 blocks/CU = 128 KiB
  // ---- tile decode: XCD swizzle -> upper-tri (I, J), J >= I ----
  int u = ((int)blockIdx.x & 7) * (NBLK / 8) + ((int)blockIdx.x >> 3);
  int I = 0, rem = u;
  while (rem >= NT - I) { rem -= NT - I; ++I; }
  const int J = I + rem;
  const int rowA0 = I * 128, colB0 = J * 128;
  const bool diag = (I == J);

  const int t = threadIdx.x;
  const int wave = t >> 6, lane = t & 63;
  const int wm = wave >> 1, wn = wave & 1;  // 2x2 waves, each 64x64 out
  const int l31 = lane & 31, kh = lane >> 5;

  // ---- staging: 2 A-chunks + 2 B-chunks (16B each) per thread per slot ----
  // slot layout (shorts): A[128 rows][32] at 0, B[128][32] at 4096. Chunk c
  // (16B): row=c>>2, phys group p=c&3 holds logical lg = p ^ ((row>>1)&3)
  // (inverse of the read-side XOR). LDS dest linear (wave-uniform + lane*16).
  int oA[2], oB[2];
#pragma unroll
  for (int i = 0; i < 2; ++i) {
    int c = i * 256 + wave * 64 + lane, row = c >> 2, p = c & 3;
    oA[i] = (rowA0 + row) * DIM + (p ^ ((row >> 1) & 3)) * 8;
    oB[i] = (colB0 + row) * DIM + (p ^ ((row >> 1) & 3)) * 8;
  }

  // ---- compute-side ds_read offsets (shorts), swizzle applied on read ----
  // Frag (32x32x16): lane reads row (blk*32 + l31), 8 bf16 at k-slice
  // k16*16 + kh*8 -> 16B-group g = k16*2 + kh, phys = g ^ ((l31>>1)&3).
  const int cls = (l31 >> 1) & 3;
  const int g0 = (kh ^ cls) * 8;        // k16=0 group offset (shorts)
  const int g1 = ((2 + kh) ^ cls) * 8;  // k16=1
  const int arow_s = (wm * 64 + l31) * 32;         // A base (shorts)
  const int brow_s = 4096 + (wn * 64 + l31) * 32;  // B base (shorts)

  f32x16 acc[2][2];
#pragma unroll
  for (int m = 0; m < 2; ++m)
#pragma unroll
    for (int n = 0; n < 2; ++n)
#pragma unroll
      for (int r = 0; r < 16; ++r) acc[m][n][r] = 0.f;

#define STAGE(dst_, k_)                                                       \
  {                                                                           \
    const unsigned short* gk = zb + (size_t)((k_) & 31) * 32;                 \
    GLD16(gk + oA[0], (dst_) + wave * 512);                                   \
    GLD16(gk + oA[1], (dst_) + 2048 + wave * 512);                            \
    GLD16(gk + oB[0], (dst_) + 4096 + wave * 512);                            \
    GLD16(gk + oB[1], (dst_) + 4096 + 2048 + wave * 512);                     \
  }

  unsigned short* cur = lds;         // slot holding tile s
  unsigned short* oth = lds + SLOT;  // slot holding tile s+1 (stage target)

  STAGE(cur, 0);
  asm volatile("s_waitcnt vmcnt(0)" ::: "memory");  // own slot-0 loads done

#pragma unroll 1
  for (int s = 0; s < DIM / 32; ++s) {
    __builtin_amdgcn_s_barrier();  // BAR_A: all waves done reading oth (s-1)
    __builtin_amdgcn_sched_barrier(0);
    STAGE(oth, s + 1);             // s=31: dummy wrap (k&31=0), never read
    asm volatile("s_waitcnt vmcnt(4)" ::: "memory");  // own slot-s loads done
    __builtin_amdgcn_s_barrier();  // BAR_B: slot s published across waves
    __builtin_amdgcn_sched_barrier(0);

    bf16x8 a00 = *(const bf16x8*)(cur + arow_s + g0);
    bf16x8 a01 = *(const bf16x8*)(cur + arow_s + g1);
    bf16x8 a10 = *(const bf16x8*)(cur + arow_s + 1024 + g0);
    bf16x8 a11 = *(const bf16x8*)(cur + arow_s + 1024 + g1);
    bf16x8 b00 = *(const bf16x8*)(cur + brow_s + g0);
    bf16x8 b01 = *(const bf16x8*)(cur + brow_s + g1);
    bf16x8 b10 = *(const bf16x8*)(cur + brow_s + 1024 + g0);
    bf16x8 b11 = *(const bf16x8*)(cur + brow_s + 1024 + g1);
    __builtin_amdgcn_s_setprio(1);
    acc[0][0] = __builtin_amdgcn_mfma_f32_32x32x16_bf16(a00, b00, acc[0][0], 0, 0, 0);
    acc[0][1] = __builtin_amdgcn_mfma_f32_32x32x16_bf16(a00, b10, acc[0][1], 0, 0, 0);
    acc[1][0] = __builtin_amdgcn_mfma_f32_32x32x16_bf16(a10, b00, acc[1][0], 0, 0, 0);
    acc[1][1] = __builtin_amdgcn_mfma_f32_32x32x16_bf16(a10, b10, acc[1][1], 0, 0, 0);
    acc[0][0] = __builtin_amdgcn_mfma_f32_32x32x16_bf16(a01, b01, acc[0][0], 0, 0, 0);
    acc[0][1] = __builtin_amdgcn_mfma_f32_32x32x16_bf16(a01, b11, acc[0][1], 0, 0, 0);
    acc[1][0] = __builtin_amdgcn_mfma_f32_32x32x16_bf16(a11, b01, acc[1][0], 0, 0, 0);
    acc[1][1] = __builtin_amdgcn_mfma_f32_32x32x16_bf16(a11, b11, acc[1][1], 0, 0, 0);
    __builtin_amdgcn_s_setprio(0);
    unsigned short* tmp_ = cur; cur = oth; oth = tmp_;  // swap buffers
  }
  asm volatile("s_waitcnt vmcnt(0) lgkmcnt(0)" ::: "memory");  // drain dummy

  // ---- epilogue: e=exp((dot-1)/T), diag masked; row/col partial sums ----
  // C/D 32x32: col = lane&31, row = (reg&3) + 8*(reg>>2) + 4*(lane>>5).
  // NO atomics: plane stores (row partials keyed (J,wn) -> planes 0..127;
  // col partials keyed (I,wm) -> planes 128..255).
  float* rplane = part + (size_t)(2 * J + wn) * TWO_N;
  float* cplane = part + (size_t)(128 + 2 * I + wm) * TWO_N;
  float csum[2] = {0.f, 0.f};
#pragma unroll
  for (int m = 0; m < 2; ++m) {
#pragma unroll
    for (int r = 0; r < 16; ++r) {
      const int grow = rowA0 + wm * 64 + m * 32 + (r & 3) + 8 * (r >> 2) + 4 * kh;
      float s = 0.f;
#pragma unroll
      for (int n = 0; n < 2; ++n) {
        const int gcol = colB0 + wn * 64 + n * 32 + l31;
        float e = exp2f((acc[m][n][r] - 1.0f) * EXP_SCALE);
        if (grow == gcol) e = 0.f;  // mask self-similarity (diag tiles)
        s += e;
        csum[n] += e;
      }
      s += __shfl_xor(s, 1); s += __shfl_xor(s, 2); s += __shfl_xor(s, 4);
      s += __shfl_xor(s, 8); s += __shfl_xor(s, 16);
      if (l31 == 0) rplane[grow] = s;  // lanes 0,32: distinct rows (kh)
    }
  }
  if (!diag) {  // off-diagonal tiles feed transposed rows via col sums
#pragma unroll
    for (int n = 0; n < 2; ++n) {
      float c = csum[n];
      c += __shfl_xor(c, 32);  // combine kh halves (same col, disjoint rows)
      if (lane < 32) cplane[colB0 + wn * 64 + n * 32 + lane] = c;
    }
  }
#undef STAGE
}

// Fold only the provably-written plane entries -> per-row term -> mean.
// For row i (Ji = i>>7): row-planes 2J+{0,1} are written iff J >= Ji;
// col-planes 128+2I+{0,1} iff I < Ji. Exactly 128 entries per row, so no
// workspace memset is needed (stale bytes are never read).
__global__ __launch_bounds__(256) void reduce_finalize_kernel(
    const float* __restrict__ part, const float* __restrict__ pos,
    float* __restrict__ out) {
  const int i = blockIdx.x * 256 + threadIdx.x;
  const int Ji = i >> 7;
  float s = 0.f;
  for (int J = Ji; J < NT; ++J)
    s += part[(size_t)(2 * J) * TWO_N + i] + part[(size_t)(2 * J + 1) * TWO_N + i];
  for (int I = 0; I < Ji; ++I)
    s += part[(size_t)(128 + 2 * I) * TWO_N + i] +
         part[(size_t)(128 + 2 * I + 1) * TWO_N + i];
  float term = TEMP_INV + logf(s) - pos[i & (NN - 1)];
#pragma unroll
  for (int off = 1; off < 64; off <<= 1) term += __shfl_xor(term, off);
  __shared__ float tmp[4];
  const int t = threadIdx.x;
  if ((t & 63) == 0) tmp[t >> 6] = term;
  __syncthreads();
  if (t == 0)
    atomicAdd(out, (tmp[0] + tmp[1] + tmp[2] + tmp[3]) * (1.0f / (float)TWO_N));
}

extern "C" void kernel_launch(void* const* d_in, const int* in_sizes, int n_in,
                              void* d_out, int out_size, void* d_ws, size_t ws_size,
                              hipStream_t stream) {
  const float* z1 = (const float*)d_in[0];
  const float* z2 = (const float*)d_in[1];
  float* out = (float*)d_out;

  char* ws = (char*)d_ws;
  unsigned short* zb = (unsigned short*)ws;            // 16 MB bf16 z
  size_t off = (size_t)TWO_N * DIM * 2;
  float* part = (float*)(ws + off);                    // 8 MB: 256 x 8192 f32
  off += (size_t)256 * TWO_N * 4;
  float* pos = (float*)(ws + off);                     // 16 KB

  hipMemsetAsync(out, 0, sizeof(float), stream);
  prep_kernel<<<NN, 256, 0, stream>>>(z1, z2, zb, pos);
  lse_kernel<<<NBLK, 256, 0, stream>>>(zb, part);
  reduce_finalize_kernel<<<TWO_N / 256, 256, 0, stream>>>(part, pos, out);
}